// Round 1
// baseline (2850.295 us; speedup 1.0000x reference)
//
#include <hip/hip_runtime.h>

#define N_CAT   100000
#define N_USERS 50000
#define DIM     64
#define N_RELM1 15
#define E_EDGES 1500000
#define NNZ_E   1500000

// K1: normsq[n][r] = sum_d (cat[n][d] * w[r][d])^2  — one wave per node
__global__ void normsq_kernel(const float* __restrict__ cat,
                              const float* __restrict__ weight,
                              float* __restrict__ normsq) {
    int gtid = blockIdx.x * blockDim.x + threadIdx.x;
    int node = gtid >> 6;
    int lane = threadIdx.x & 63;
    if (node >= N_CAT) return;
    float c = cat[node * DIM + lane];
    float wl[N_RELM1];
#pragma unroll
    for (int r = 0; r < N_RELM1; ++r) wl[r] = weight[r * DIM + lane];
    float myval = 0.f;
#pragma unroll
    for (int r = 0; r < N_RELM1; ++r) {
        float t = c * wl[r];
        float s = t * t;
#pragma unroll
        for (int off = 1; off < 64; off <<= 1)
            s += __shfl_xor(s, off, 64);
        if (lane == r) myval = s;
    }
    if (lane < N_RELM1) normsq[node * N_RELM1 + lane] = myval;
}

// K2: att[e] = normsq[head][r]*normsq[tail][r]; atomicMax into segmax (att>=0)
__global__ void att_kernel(const int* __restrict__ head,
                           const int* __restrict__ tail,
                           const int* __restrict__ etype,
                           const float* __restrict__ normsq,
                           float* __restrict__ att,
                           unsigned int* __restrict__ segmax) {
    int e = blockIdx.x * blockDim.x + threadIdx.x;
    if (e >= E_EDGES) return;
    int h = head[e], t = tail[e], r = etype[e] - 1;
    float a = normsq[h * N_RELM1 + r] * normsq[t * N_RELM1 + r];
    att[e] = a;
    atomicMax(&segmax[h], __float_as_uint(a));
}

// K3: ev = exp(att - segmax[head]); segsum[head] += ev  (ev overwrites att)
__global__ void expsum_kernel(const int* __restrict__ head,
                              float* __restrict__ attev,
                              const unsigned int* __restrict__ segmax,
                              float* __restrict__ segsum) {
    int e = blockIdx.x * blockDim.x + threadIdx.x;
    if (e >= E_EDGES) return;
    int h = head[e];
    float ev = expf(attev[e] - __uint_as_float(segmax[h]));
    attev[e] = ev;
    atomicAdd(&segsum[h], ev);
}

// K4: category_agg[head] += (ev/segsum[head]) * cat[tail] * w[r] — 16 thr/edge
__global__ void cat_scatter_kernel(const int* __restrict__ head,
                                   const int* __restrict__ tail,
                                   const int* __restrict__ etype,
                                   const float* __restrict__ ev,
                                   const float* __restrict__ segsum,
                                   const float* __restrict__ cat,
                                   const float* __restrict__ weight,
                                   float* __restrict__ catagg) {
    int idx = blockIdx.x * blockDim.x + threadIdx.x;
    if (idx >= E_EDGES * 16) return;
    int e = idx >> 4, g = idx & 15;
    int h = head[e], t = tail[e], r = etype[e] - 1;
    float w = ev[e] / segsum[h];
    float4 c  = ((const float4*)(cat + (size_t)t * DIM))[g];
    float4 rl = ((const float4*)(weight + r * DIM))[g];
    float* dst = catagg + (size_t)h * DIM + g * 4;
    atomicAdd(dst + 0, w * c.x * rl.x);
    atomicAdd(dst + 1, w * c.y * rl.y);
    atomicAdd(dst + 2, w * c.z * rl.z);
    atomicAdd(dst + 3, w * c.w * rl.w);
}

// K5: user_agg[iu] += val * cat[ic] — 16 threads/nnz
__global__ void user_scatter_kernel(const int* __restrict__ iu,
                                    const int* __restrict__ ic,
                                    const float* __restrict__ val,
                                    const float* __restrict__ cat,
                                    float* __restrict__ useragg) {
    int idx = blockIdx.x * blockDim.x + threadIdx.x;
    if (idx >= NNZ_E * 16) return;
    int e = idx >> 4, g = idx & 15;
    int u = iu[e], c = ic[e];
    float v = val[e];
    float4 cv = ((const float4*)(cat + (size_t)c * DIM))[g];
    float* dst = useragg + (size_t)u * DIM + g * 4;
    atomicAdd(dst + 0, v * cv.x);
    atomicAdd(dst + 1, v * cv.y);
    atomicAdd(dst + 2, v * cv.z);
    atomicAdd(dst + 3, v * cv.w);
}

// K6: user_agg *= (1 + softmax(u@W^T) @ W) — one wave per user
__global__ void user_gate_kernel(const float* __restrict__ uemb,
                                 const float* __restrict__ weight,
                                 float* __restrict__ useragg) {
    int gtid = blockIdx.x * blockDim.x + threadIdx.x;
    int user = gtid >> 6;
    int lane = threadIdx.x & 63;
    if (user >= N_USERS) return;
    float u = uemb[user * DIM + lane];
    float wl[N_RELM1];
#pragma unroll
    for (int r = 0; r < N_RELM1; ++r) wl[r] = weight[r * DIM + lane];
    float s[N_RELM1];
#pragma unroll
    for (int r = 0; r < N_RELM1; ++r) {
        float p = u * wl[r];
#pragma unroll
        for (int off = 1; off < 64; off <<= 1)
            p += __shfl_xor(p, off, 64);
        s[r] = p;
    }
    float m = s[0];
#pragma unroll
    for (int r = 1; r < N_RELM1; ++r) m = fmaxf(m, s[r]);
    float Z = 0.f;
#pragma unroll
    for (int r = 0; r < N_RELM1; ++r) { s[r] = expf(s[r] - m); Z += s[r]; }
    float g = 0.f;
#pragma unroll
    for (int r = 0; r < N_RELM1; ++r) g += s[r] * wl[r];
    g /= Z;
    size_t o = (size_t)user * DIM + lane;
    useragg[o] = useragg[o] * (1.f + g);
}

extern "C" void kernel_launch(void* const* d_in, const int* in_sizes, int n_in,
                              void* d_out, int out_size, void* d_ws, size_t ws_size,
                              hipStream_t stream) {
    const float* cat    = (const float*)d_in[0];
    const float* uemb   = (const float*)d_in[1];
    const int*   eidx   = (const int*)d_in[2];
    const int*   etype  = (const int*)d_in[3];
    const int*   iidx   = (const int*)d_in[4];
    const float* ival   = (const float*)d_in[5];
    const float* weight = (const float*)d_in[6];

    float* catagg  = (float*)d_out;                       // N_CAT*64
    float* useragg = (float*)d_out + (size_t)N_CAT * DIM; // N_USERS*64

    float* ws = (float*)d_ws;
    float*        normsq = ws;                         // 1,500,000
    float*        attev  = ws + 1500000;               // 1,500,000
    unsigned int* segmax = (unsigned int*)(ws + 3000000); // 100,000
    float*        segsum = ws + 3100000;               // 100,000

    const int* head = eidx;
    const int* tail = eidx + E_EDGES;
    const int* iu   = iidx;
    const int* ic   = iidx + NNZ_E;

    // zero accumulators (att>=0 so segmax identity = 0 bits)
    hipMemsetAsync(d_out, 0, (size_t)(N_CAT + N_USERS) * DIM * sizeof(float), stream);
    hipMemsetAsync(segmax, 0, (size_t)200000 * sizeof(float), stream);

    normsq_kernel<<<(N_CAT * 64 + 255) / 256, 256, 0, stream>>>(cat, weight, normsq);
    att_kernel<<<(E_EDGES + 255) / 256, 256, 0, stream>>>(head, tail, etype, normsq, attev, segmax);
    expsum_kernel<<<(E_EDGES + 255) / 256, 256, 0, stream>>>(head, attev, segmax, segsum);
    cat_scatter_kernel<<<(E_EDGES * 16 + 255) / 256, 256, 0, stream>>>(
        head, tail, etype, attev, segsum, cat, weight, catagg);
    user_scatter_kernel<<<(NNZ_E * 16 + 255) / 256, 256, 0, stream>>>(
        iu, ic, ival, cat, useragg);
    user_gate_kernel<<<(N_USERS * 64 + 255) / 256, 256, 0, stream>>>(uemb, weight, useragg);
}

// Round 2
// 843.606 us; speedup vs baseline: 3.3787x; 3.3787x over previous
//
#include <hip/hip_runtime.h>

#define N_CAT   100000
#define N_USERS 50000
#define DIM     64
#define N_RELM1 15
#define E_EDGES 1500000
#define NNZ_E   1500000

// K1: normsq[n][r] = sum_d (cat[n][d] * w[r][d])^2  — one wave per node
__global__ void normsq_kernel(const float* __restrict__ cat,
                              const float* __restrict__ weight,
                              float* __restrict__ normsq) {
    int gtid = blockIdx.x * blockDim.x + threadIdx.x;
    int node = gtid >> 6;
    int lane = threadIdx.x & 63;
    if (node >= N_CAT) return;
    float c = cat[node * DIM + lane];
    float myval = 0.f;
#pragma unroll
    for (int r = 0; r < N_RELM1; ++r) {
        float t = c * weight[r * DIM + lane];
        float s = t * t;
#pragma unroll
        for (int off = 1; off < 64; off <<= 1)
            s += __shfl_xor(s, off, 64);
        if (lane == r) myval = s;
    }
    if (lane < N_RELM1) normsq[node * N_RELM1 + lane] = myval;
}

// K2: histograms of head[] and iu[]
__global__ void hist_kernel(const int* __restrict__ head, const int* __restrict__ iu,
                            int* __restrict__ hcnt, int* __restrict__ ucnt) {
    int e = blockIdx.x * blockDim.x + threadIdx.x;
    if (e < E_EDGES) atomicAdd(&hcnt[head[e]], 1);
    if (e < NNZ_E)  atomicAdd(&ucnt[iu[e]], 1);
}

// K3: two exclusive scans (block 0: head counts -> hoff; block 1: user counts -> uoff)
__global__ void scan2_kernel(const int* __restrict__ hcnt, int* __restrict__ hoff,
                             const int* __restrict__ ucnt, int* __restrict__ uoff) {
    const int* cnt = (blockIdx.x == 0) ? hcnt : ucnt;
    int*       off = (blockIdx.x == 0) ? hoff : uoff;
    int          n = (blockIdx.x == 0) ? N_CAT : N_USERS;
    __shared__ int wsum[16];
    __shared__ int scarry;
    int lane = threadIdx.x & 63;
    int wid  = threadIdx.x >> 6;
    if (threadIdx.x == 0) scarry = 0;
    __syncthreads();
    for (int base = 0; base < n; base += 1024) {
        int i = base + threadIdx.x;
        int v = (i < n) ? cnt[i] : 0;
        int s = v;
#pragma unroll
        for (int d = 1; d < 64; d <<= 1) {
            int t = __shfl_up(s, d, 64);
            if (lane >= d) s += t;
        }
        if (lane == 63) wsum[wid] = s;
        __syncthreads();
        int wprefix = 0, total = 0;
#pragma unroll
        for (int w = 0; w < 16; ++w) {
            int ws_ = wsum[w];
            wprefix += (w < wid) ? ws_ : 0;
            total += ws_;
        }
        if (i < n) off[i] = scarry + wprefix + s - v;
        __syncthreads();
        if (threadIdx.x == 0) scarry += total;
        __syncthreads();
    }
    if (threadIdx.x == 0) off[n] = scarry;
}

// K4: scatter edge ids into sorted order (cursor arrays pre-loaded with offsets)
__global__ void scatter_kernel(const int* __restrict__ head, const int* __restrict__ iu,
                               int* __restrict__ hcur, int* __restrict__ ucur,
                               int* __restrict__ esorted, int* __restrict__ nsorted) {
    int e = blockIdx.x * blockDim.x + threadIdx.x;
    if (e < E_EDGES) { int p = atomicAdd(&hcur[head[e]], 1); esorted[p] = e; }
    if (e < NNZ_E)  { int p = atomicAdd(&ucur[iu[e]], 1);  nsorted[p] = e; }
}

// K5: per-head online-softmax aggregation — one wave per head, no atomics
__global__ void cat_agg_kernel(const int* __restrict__ esorted,
                               const int* __restrict__ hoff,
                               const int* __restrict__ tail,
                               const int* __restrict__ etype,
                               const float* __restrict__ normsq,
                               const float* __restrict__ cat,
                               const float* __restrict__ weight,
                               float* __restrict__ catagg) {
    int gtid = blockIdx.x * blockDim.x + threadIdx.x;
    int h = gtid >> 6;
    int lane = threadIdx.x & 63;
    if (h >= N_CAT) return;
    int s0 = hoff[h], s1 = hoff[h + 1];
    float acc = 0.f, Z = 0.f, m = -1e30f;
    for (int base = s0; base < s1; base += 64) {
        int cn = min(64, s1 - base);
        float att = -1e30f;
        int pk = 0;
        if (lane < cn) {
            int e = esorted[base + lane];
            int t = tail[e], r = etype[e] - 1;
            pk = (t << 4) | r;
            att = normsq[h * N_RELM1 + r] * normsq[(size_t)t * N_RELM1 + r];
        }
        float cm = att;
#pragma unroll
        for (int off = 1; off < 64; off <<= 1)
            cm = fmaxf(cm, __shfl_xor(cm, off, 64));
        float nm = fmaxf(m, cm);
        float scale = expf(m - nm);
        acc *= scale; Z *= scale; m = nm;
        float w_lane = (lane < cn) ? expf(att - m) : 0.f;
        float zs = w_lane;
#pragma unroll
        for (int off = 1; off < 64; off <<= 1)
            zs += __shfl_xor(zs, off, 64);
        Z += zs;
        for (int j = 0; j < cn; ++j) {
            float wj = __shfl(w_lane, j, 64);
            int pkj  = __shfl(pk, j, 64);
            int tj = pkj >> 4, rj = pkj & 15;
            acc += wj * cat[(size_t)tj * DIM + lane] * weight[rj * DIM + lane];
        }
    }
    catagg[(size_t)h * DIM + lane] = (s1 > s0) ? acc / Z : 0.f;
}

// K6: per-user aggregation + fused softmax gating — one wave per user
__global__ void user_agg_kernel(const int* __restrict__ nsorted,
                                const int* __restrict__ uoff,
                                const int* __restrict__ ic,
                                const float* __restrict__ ival,
                                const float* __restrict__ cat,
                                const float* __restrict__ uemb,
                                const float* __restrict__ weight,
                                float* __restrict__ useragg) {
    int gtid = blockIdx.x * blockDim.x + threadIdx.x;
    int u = gtid >> 6;
    int lane = threadIdx.x & 63;
    if (u >= N_USERS) return;
    int s0 = uoff[u], s1 = uoff[u + 1];
    float acc = 0.f;
    for (int base = s0; base < s1; base += 64) {
        int cn = min(64, s1 - base);
        int c = 0; float v = 0.f;
        if (lane < cn) {
            int e = nsorted[base + lane];
            c = ic[e]; v = ival[e];
        }
        for (int j = 0; j < cn; ++j) {
            int   cj = __shfl(c, j, 64);
            float vj = __shfl(v, j, 64);
            acc += vj * cat[(size_t)cj * DIM + lane];
        }
    }
    // gating: g = (softmax(u@W^T) @ W)[lane]
    float uv = uemb[(size_t)u * DIM + lane];
    float wl[N_RELM1], s[N_RELM1];
#pragma unroll
    for (int r = 0; r < N_RELM1; ++r) wl[r] = weight[r * DIM + lane];
#pragma unroll
    for (int r = 0; r < N_RELM1; ++r) {
        float p = uv * wl[r];
#pragma unroll
        for (int off = 1; off < 64; off <<= 1)
            p += __shfl_xor(p, off, 64);
        s[r] = p;
    }
    float m = s[0];
#pragma unroll
    for (int r = 1; r < N_RELM1; ++r) m = fmaxf(m, s[r]);
    float Z = 0.f;
#pragma unroll
    for (int r = 0; r < N_RELM1; ++r) { s[r] = expf(s[r] - m); Z += s[r]; }
    float g = 0.f;
#pragma unroll
    for (int r = 0; r < N_RELM1; ++r) g += s[r] * wl[r];
    g /= Z;
    useragg[(size_t)u * DIM + lane] = acc * (1.f + g);
}

extern "C" void kernel_launch(void* const* d_in, const int* in_sizes, int n_in,
                              void* d_out, int out_size, void* d_ws, size_t ws_size,
                              hipStream_t stream) {
    const float* cat    = (const float*)d_in[0];
    const float* uemb   = (const float*)d_in[1];
    const int*   eidx   = (const int*)d_in[2];
    const int*   etype  = (const int*)d_in[3];
    const int*   iidx   = (const int*)d_in[4];
    const float* ival   = (const float*)d_in[5];
    const float* weight = (const float*)d_in[6];

    float* catagg  = (float*)d_out;
    float* useragg = (float*)d_out + (size_t)N_CAT * DIM;

    // workspace layout (4-byte words)
    int* ws = (int*)d_ws;
    float* normsq  = (float*)ws;              // 1,500,000
    int*   hoff    = ws + 1500000;            // 100,001
    int*   uoff    = ws + 1600001;            // 50,001
    int*   hcnt    = ws + 1650002;            // 100,000 (count, then cursor)
    int*   ucnt    = ws + 1750002;            // 50,000  (count, then cursor)
    int*   esorted = ws + 1800002;            // 1,500,000
    int*   nsorted = ws + 3300002;            // 1,500,000

    const int* head = eidx;
    const int* tail = eidx + E_EDGES;
    const int* iu   = iidx;
    const int* ic   = iidx + NNZ_E;

    hipMemsetAsync(hcnt, 0, (size_t)150000 * sizeof(int), stream); // hcnt+ucnt contiguous

    normsq_kernel<<<(N_CAT * 64 + 255) / 256, 256, 0, stream>>>(cat, weight, normsq);
    hist_kernel<<<(E_EDGES + 255) / 256, 256, 0, stream>>>(head, iu, hcnt, ucnt);
    scan2_kernel<<<2, 1024, 0, stream>>>(hcnt, hoff, ucnt, uoff);
    // cursors = copy of offsets
    hipMemcpyAsync(hcnt, hoff, (size_t)N_CAT * sizeof(int), hipMemcpyDeviceToDevice, stream);
    hipMemcpyAsync(ucnt, uoff, (size_t)N_USERS * sizeof(int), hipMemcpyDeviceToDevice, stream);
    scatter_kernel<<<(E_EDGES + 255) / 256, 256, 0, stream>>>(head, iu, hcnt, ucnt, esorted, nsorted);
    cat_agg_kernel<<<(N_CAT * 64 + 255) / 256, 256, 0, stream>>>(
        esorted, hoff, tail, etype, normsq, cat, weight, catagg);
    user_agg_kernel<<<(N_USERS * 64 + 255) / 256, 256, 0, stream>>>(
        nsorted, uoff, ic, ival, cat, uemb, weight, useragg);
}

// Round 3
// 584.946 us; speedup vs baseline: 4.8727x; 1.4422x over previous
//
#include <hip/hip_runtime.h>

#define N_CAT   100000
#define N_USERS 50000
#define DIM     64
#define N_RELM1 15
#define E_EDGES 1500000
#define NNZ_E   1500000
#define HR      12500   // N_CAT/8
#define UR      6250    // N_USERS/8
#define NXCD    8

// K1: normsq[n][r] = sum_d (cat[n][d] * w[r][d])^2  — one wave per node
__global__ void normsq_kernel(const float* __restrict__ cat,
                              const float* __restrict__ weight,
                              float* __restrict__ normsq) {
    int gtid = blockIdx.x * blockDim.x + threadIdx.x;
    int node = gtid >> 6;
    int lane = threadIdx.x & 63;
    if (node >= N_CAT) return;
    float c = cat[node * DIM + lane];
    float myval = 0.f;
#pragma unroll
    for (int r = 0; r < N_RELM1; ++r) {
        float t = c * weight[r * DIM + lane];
        float s = t * t;
#pragma unroll
        for (int off = 1; off < 64; off <<= 1)
            s += __shfl_xor(s, off, 64);
        if (lane == r) myval = s;
    }
    if (lane < N_RELM1) normsq[node * N_RELM1 + lane] = myval;
}

// K2: XCD-grouped histograms — group g only counts its own 1/8 id-range
__global__ void hist_kernel(const int* __restrict__ head, const int* __restrict__ iu,
                            int* __restrict__ hcnt, int* __restrict__ ucnt) {
    int g  = blockIdx.x & 7;
    int lb = blockIdx.x >> 3;
    int stride = (gridDim.x >> 3) * blockDim.x;
    for (int e = lb * blockDim.x + threadIdx.x; e < E_EDGES; e += stride) {
        int h = head[e];
        if (h / HR == g) atomicAdd(&hcnt[h], 1);
        int u = iu[e];
        if (u / UR == g) atomicAdd(&ucnt[u], 1);
    }
}

// K3a: per-1024-block exclusive scan; block totals out
__global__ void scanA_kernel(const int* __restrict__ hcnt, int* __restrict__ hoff,
                             const int* __restrict__ ucnt, int* __restrict__ uoff,
                             int* __restrict__ hbtot, int* __restrict__ ubtot) {
    __shared__ int wsum[16];
    int bid = blockIdx.x;
    const int* src; int* dst; int* btot; int n; int base;
    if (bid < 98) { src = hcnt; dst = hoff; btot = hbtot + bid; n = N_CAT;  base = bid * 1024; }
    else { int b = bid - 98; src = ucnt; dst = uoff; btot = ubtot + b; n = N_USERS; base = b * 1024; }
    int i = base + threadIdx.x;
    int lane = threadIdx.x & 63, wid = threadIdx.x >> 6;
    int v = (i < n) ? src[i] : 0;
    int s = v;
#pragma unroll
    for (int d = 1; d < 64; d <<= 1) {
        int t = __shfl_up(s, d, 64);
        if (lane >= d) s += t;
    }
    if (lane == 63) wsum[wid] = s;
    __syncthreads();
    int wpre = 0, tot = 0;
#pragma unroll
    for (int w = 0; w < 16; ++w) {
        int x = wsum[w];
        if (w < wid) wpre += x;
        tot += x;
    }
    if (i < n) dst[i] = wpre + s - v;
    if (threadIdx.x == 0) *btot = tot;
}

// K3b: exclusive scan of block totals (block 0: 98 cat totals, block 1: 49 user totals)
__global__ void scanB_kernel(int* __restrict__ hbtot, int* __restrict__ ubtot) {
    int* b = (blockIdx.x == 0) ? hbtot : ubtot;
    int n  = (blockIdx.x == 0) ? 98 : 49;
    __shared__ int w0;
    int lane = threadIdx.x & 63, wid = threadIdx.x >> 6;
    int i = threadIdx.x;
    int v = (i < n) ? b[i] : 0;
    int s = v;
#pragma unroll
    for (int d = 1; d < 64; d <<= 1) {
        int t = __shfl_up(s, d, 64);
        if (lane >= d) s += t;
    }
    if (wid == 0 && lane == 63) w0 = s;
    __syncthreads();
    int add = (wid == 1) ? w0 : 0;
    if (i < n) b[i] = add + s - v;
}

// K3c: add block offsets, materialize cursors (reusing cnt arrays), write totals
__global__ void scanC_kernel(int* __restrict__ hoff, int* __restrict__ uoff,
                             const int* __restrict__ hbtot, const int* __restrict__ ubtot,
                             int* __restrict__ hcur, int* __restrict__ ucur) {
    int i = blockIdx.x * 1024 + threadIdx.x;
    if (i < N_CAT) {
        int v = hoff[i] + hbtot[i >> 10];
        hoff[i] = v; hcur[i] = v;
    } else if (i < N_CAT + N_USERS) {
        int j = i - N_CAT;
        int v = uoff[j] + ubtot[j >> 10];
        uoff[j] = v; ucur[j] = v;
    }
    if (i == 0) { hoff[N_CAT] = E_EDGES; uoff[N_USERS] = NNZ_E; }
}

// K4: XCD-grouped scatter with packed payloads — group g commits only its range,
// so each destination region is written from a single XCD's L2 (no line bouncing)
__global__ void scatter_kernel(const int* __restrict__ head, const int* __restrict__ tail,
                               const int* __restrict__ etype,
                               const int* __restrict__ iu, const int* __restrict__ ic,
                               const float* __restrict__ ival,
                               int* __restrict__ hcur, int* __restrict__ ucur,
                               int* __restrict__ esorted, int2* __restrict__ nsorted2) {
    int g  = blockIdx.x & 7;
    int lb = blockIdx.x >> 3;
    int stride = (gridDim.x >> 3) * blockDim.x;
    for (int e = lb * blockDim.x + threadIdx.x; e < E_EDGES; e += stride) {
        int h = head[e];
        if (h / HR == g) {
            int p = atomicAdd(&hcur[h], 1);
            esorted[p] = (tail[e] << 4) | (etype[e] - 1);
        }
        int u = iu[e];
        if (u / UR == g) {
            int p = atomicAdd(&ucur[u], 1);
            nsorted2[p] = make_int2(ic[e], __float_as_int(ival[e]));
        }
    }
}

// K5: per-head online-softmax aggregation — swizzled so head-range g runs on XCD g
__global__ void cat_agg_kernel(const int* __restrict__ esorted,
                               const int* __restrict__ hoff,
                               const float* __restrict__ normsq,
                               const float* __restrict__ cat,
                               const float* __restrict__ weight,
                               float* __restrict__ catagg) {
    int g = blockIdx.x & 7, lb = blockIdx.x >> 3;
    int wid = threadIdx.x >> 6, lane = threadIdx.x & 63;
    int h = g * HR + lb * 4 + wid;
    int s0 = hoff[h], s1 = hoff[h + 1];
    float acc = 0.f, Z = 0.f, m = -1e30f;
    for (int base = s0; base < s1; base += 64) {
        int cn = min(64, s1 - base);
        float att = -1e30f;
        int pk = 0;
        if (lane < cn) {
            pk = esorted[base + lane];
            int t = pk >> 4, r = pk & 15;
            att = normsq[h * N_RELM1 + r] * normsq[(size_t)t * N_RELM1 + r];
        }
        float cm = att;
#pragma unroll
        for (int off = 1; off < 64; off <<= 1)
            cm = fmaxf(cm, __shfl_xor(cm, off, 64));
        float nm = fmaxf(m, cm);
        float scale = expf(m - nm);
        acc *= scale; Z *= scale; m = nm;
        float w_lane = (lane < cn) ? expf(att - m) : 0.f;
        float zs = w_lane;
#pragma unroll
        for (int off = 1; off < 64; off <<= 1)
            zs += __shfl_xor(zs, off, 64);
        Z += zs;
        for (int j = 0; j < cn; ++j) {
            float wj = __shfl(w_lane, j, 64);
            int pkj  = __shfl(pk, j, 64);
            int tj = pkj >> 4, rj = pkj & 15;
            acc += wj * cat[(size_t)tj * DIM + lane] * weight[rj * DIM + lane];
        }
    }
    catagg[(size_t)h * DIM + lane] = (s1 > s0) ? acc / Z : 0.f;
}

// K6: per-user aggregation + fused softmax gating — swizzled to matching XCD
__global__ void user_agg_kernel(const int2* __restrict__ nsorted2,
                                const int* __restrict__ uoff,
                                const float* __restrict__ cat,
                                const float* __restrict__ uemb,
                                const float* __restrict__ weight,
                                float* __restrict__ useragg) {
    int g = blockIdx.x & 7, lb = blockIdx.x >> 3;
    int wid = threadIdx.x >> 6, lane = threadIdx.x & 63;
    int lu = lb * 4 + wid;
    if (lu >= UR) return;
    int u = g * UR + lu;
    int s0 = uoff[u], s1 = uoff[u + 1];
    float acc = 0.f;
    for (int base = s0; base < s1; base += 64) {
        int cn = min(64, s1 - base);
        int c = 0; float v = 0.f;
        if (lane < cn) {
            int2 pay = nsorted2[base + lane];
            c = pay.x; v = __int_as_float(pay.y);
        }
        for (int j = 0; j < cn; ++j) {
            int   cj = __shfl(c, j, 64);
            float vj = __shfl(v, j, 64);
            acc += vj * cat[(size_t)cj * DIM + lane];
        }
    }
    // gating: g = (softmax(u@W^T) @ W)[lane]
    float uv = uemb[(size_t)u * DIM + lane];
    float wl[N_RELM1], s[N_RELM1];
#pragma unroll
    for (int r = 0; r < N_RELM1; ++r) wl[r] = weight[r * DIM + lane];
#pragma unroll
    for (int r = 0; r < N_RELM1; ++r) {
        float p = uv * wl[r];
#pragma unroll
        for (int off = 1; off < 64; off <<= 1)
            p += __shfl_xor(p, off, 64);
        s[r] = p;
    }
    float mx = s[0];
#pragma unroll
    for (int r = 1; r < N_RELM1; ++r) mx = fmaxf(mx, s[r]);
    float Z = 0.f;
#pragma unroll
    for (int r = 0; r < N_RELM1; ++r) { s[r] = expf(s[r] - mx); Z += s[r]; }
    float gt = 0.f;
#pragma unroll
    for (int r = 0; r < N_RELM1; ++r) gt += s[r] * wl[r];
    gt /= Z;
    useragg[(size_t)u * DIM + lane] = acc * (1.f + gt);
}

extern "C" void kernel_launch(void* const* d_in, const int* in_sizes, int n_in,
                              void* d_out, int out_size, void* d_ws, size_t ws_size,
                              hipStream_t stream) {
    const float* cat    = (const float*)d_in[0];
    const float* uemb   = (const float*)d_in[1];
    const int*   eidx   = (const int*)d_in[2];
    const int*   etype  = (const int*)d_in[3];
    const int*   iidx   = (const int*)d_in[4];
    const float* ival   = (const float*)d_in[5];
    const float* weight = (const float*)d_in[6];

    float* catagg  = (float*)d_out;
    float* useragg = (float*)d_out + (size_t)N_CAT * DIM;

    // workspace layout (4-byte words)
    int* ws = (int*)d_ws;
    float* normsq   = (float*)ws;             // 1,500,000
    int*   hoff     = ws + 1500000;           // 100,001
    int*   uoff     = ws + 1600001;           // 50,001
    int*   hcnt     = ws + 1650002;           // 100,000 (counts, then cursors)
    int*   ucnt     = ws + 1750002;           // 50,000
    int*   hbtot    = ws + 1800002;           // 128
    int*   ubtot    = ws + 1800130;           // 128
    int*   esorted  = ws + 1800258;           // 1,500,000
    int2*  nsorted2 = (int2*)(ws + 3300258);  // 3,000,000 ints (8B-aligned offset)

    const int* head = eidx;
    const int* tail = eidx + E_EDGES;
    const int* iu   = iidx;
    const int* ic   = iidx + NNZ_E;

    hipMemsetAsync(hcnt, 0, (size_t)150000 * sizeof(int), stream); // hcnt+ucnt contiguous

    normsq_kernel<<<(N_CAT * 64 + 255) / 256, 256, 0, stream>>>(cat, weight, normsq);
    hist_kernel<<<2048, 256, 0, stream>>>(head, iu, hcnt, ucnt);
    scanA_kernel<<<98 + 49, 1024, 0, stream>>>(hcnt, hoff, ucnt, uoff, hbtot, ubtot);
    scanB_kernel<<<2, 128, 0, stream>>>(hbtot, ubtot);
    scanC_kernel<<<147, 1024, 0, stream>>>(hoff, uoff, hbtot, ubtot, hcnt, ucnt);
    scatter_kernel<<<2048, 256, 0, stream>>>(head, tail, etype, iu, ic, ival,
                                             hcnt, ucnt, esorted, nsorted2);
    cat_agg_kernel<<<25000, 256, 0, stream>>>(esorted, hoff, normsq, cat, weight, catagg);
    user_agg_kernel<<<8 * 1563, 256, 0, stream>>>(nsorted2, uoff, cat, uemb, weight, useragg);
}